// Round 1
// baseline (300.011 us; speedup 1.0000x reference)
//
#include <hip/hip_runtime.h>

// MSCALE = (0.1 * ln(SCALING=4) + 1.0) * ATTN_FACTOR=1.0
#define MSCALE 1.1386294361119891f

// Output layout (flat, concatenated return order):
//   cos: (1, L, 128) fp32   at out[0 .. L*128)
//   sin: (1, L, 128) fp32   at out[L*128 .. 2*L*128)
// Each row: cols [0..64) = freqs, cols [64..128) = same freqs duplicated.

__global__ void yarn_rope_kernel(const int* __restrict__ pos_ids,
                                 const float* __restrict__ inv_freq,
                                 const float* __restrict__ wavelengths,
                                 float* __restrict__ out,
                                 int L, long long sin_off) {
    int gid = blockIdx.x * blockDim.x + threadIdx.x;
    int d = gid & 63;          // frequency index, lane-contiguous
    int l = gid >> 6;          // position
    if (l >= L) return;

    int   w   = (int)wavelengths[d];   // round(2*pi / inv_freq) >= 1
    float ifr = inv_freq[d];

    int idx = l % w;                   // idx <= l < L, safe gather
    float pos = (float)pos_ids[idx];
    float f = pos * ifr;               // f in [0, 2*pi) -- small arg, exact trig

    float c = cosf(f) * MSCALE;
    float s = sinf(f) * MSCALE;

    long long base = (long long)l * 128 + d;
    out[base]           = c;
    out[base + 64]      = c;
    out[sin_off + base]       = s;
    out[sin_off + base + 64]  = s;
}

extern "C" void kernel_launch(void* const* d_in, const int* in_sizes, int n_in,
                              void* d_out, int out_size, void* d_ws, size_t ws_size,
                              hipStream_t stream) {
    // inputs: [0]=x (unused, fp32), [1]=position_ids (int32), [2]=r_inv_freq (fp32), [3]=r_wavelengths (fp32)
    const int*   pos_ids = (const int*)d_in[1];
    const float* inv_freq = (const float*)d_in[2];
    const float* wav      = (const float*)d_in[3];
    float* out = (float*)d_out;

    int L = in_sizes[1];                  // 16384
    long long sin_off = (long long)out_size / 2;   // cos block size = L*128

    int total = L * 64;
    int block = 256;
    int grid = (total + block - 1) / block;
    yarn_rope_kernel<<<grid, block, 0, stream>>>(pos_ids, inv_freq, wav, out, L, sin_off);
}

// Round 3
// 298.870 us; speedup vs baseline: 1.0038x; 1.0038x over previous
//
#include <hip/hip_runtime.h>

// MSCALE = (0.1 * ln(SCALING=4) + 1.0) * ATTN_FACTOR=1.0
#define MSCALE 1.1386294361119891f
#define RPT 2   // consecutive rows per thread (step-1 lets the modulo be incremental)

// Output layout (flat, concatenated return order):
//   cos: (1, L, 128) fp32  at out[0 .. L*128)
//   sin: (1, L, 128) fp32  at out[L*128 .. 2*L*128)
// Each row: cols [0..64) = freqs, cols [64..128) = identical duplicate.
//
// Thread t in a 256-thread block: g = t&15 owns frequency columns [4g, 4g+4),
// r = t>>4 picks the row group; each thread handles RPT consecutive rows.
// Lanes 0..15 of a wave write one contiguous 256 B row-half per float4 store.

__global__ __launch_bounds__(256) void yarn_rope_kernel(
        const int*   __restrict__ pos_ids,
        const float* __restrict__ inv_freq,
        const float* __restrict__ wavelengths,
        float*       __restrict__ out,
        int L, int sin_off) {
    int t = threadIdx.x;
    int g = t & 15;            // d-group: columns [4g, 4g+4)
    int r = t >> 4;            // 0..15
    int l0 = (blockIdx.x * 16 + r) * RPT;
    if (l0 >= L) return;
    int d = g * 4;

    float4 ifr = *(const float4*)(inv_freq + d);
    float4 wv  = *(const float4*)(wavelengths + d);
    int w0 = (int)wv.x, w1 = (int)wv.y, w2 = (int)wv.z, w3 = (int)wv.w;

    // one runtime divide per frequency, then incremental (step 1 < min w = 6)
    int i0 = l0 % w0, i1 = l0 % w1, i2 = l0 % w2, i3 = l0 % w3;

    #pragma unroll
    for (int k = 0; k < RPT; ++k) {
        int l = l0 + k;

        float f0 = (float)pos_ids[i0] * ifr.x;
        float f1 = (float)pos_ids[i1] * ifr.y;
        float f2 = (float)pos_ids[i2] * ifr.z;
        float f3 = (float)pos_ids[i3] * ifr.w;

        float4 c, s;
        // args are in [0, 2*pi): native sin/cos is plenty accurate here
        __sincosf(f0, &s.x, &c.x);
        __sincosf(f1, &s.y, &c.y);
        __sincosf(f2, &s.z, &c.z);
        __sincosf(f3, &s.w, &c.w);
        c.x *= MSCALE; c.y *= MSCALE; c.z *= MSCALE; c.w *= MSCALE;
        s.x *= MSCALE; s.y *= MSCALE; s.z *= MSCALE; s.w *= MSCALE;

        int base = l * 128 + d;
        *(float4*)(out + base)                = c;   // cols [d, d+4)
        *(float4*)(out + base + 64)           = c;   // duplicated half
        *(float4*)(out + sin_off + base)      = s;
        *(float4*)(out + sin_off + base + 64) = s;

        i0 = (i0 + 1 == w0) ? 0 : i0 + 1;
        i1 = (i1 + 1 == w1) ? 0 : i1 + 1;
        i2 = (i2 + 1 == w2) ? 0 : i2 + 1;
        i3 = (i3 + 1 == w3) ? 0 : i3 + 1;
    }
}

extern "C" void kernel_launch(void* const* d_in, const int* in_sizes, int n_in,
                              void* d_out, int out_size, void* d_ws, size_t ws_size,
                              hipStream_t stream) {
    // inputs: [0]=x (unused), [1]=position_ids (int32), [2]=r_inv_freq (fp32), [3]=r_wavelengths (fp32)
    const int*   pos_ids  = (const int*)d_in[1];
    const float* inv_freq = (const float*)d_in[2];
    const float* wav      = (const float*)d_in[3];
    float* out = (float*)d_out;

    int L = in_sizes[1];              // 16384
    int sin_off = out_size / 2;       // L*128 = 2,097,152

    int rows_per_block = 16 * RPT;    // 32
    int grid = (L + rows_per_block - 1) / rows_per_block;   // 512 blocks
    yarn_rope_kernel<<<grid, 256, 0, stream>>>(pos_ids, inv_freq, wav, out, L, sin_off);
}